// Round 3
// baseline (15039.571 us; speedup 1.0000x reference)
//
#include <hip/hip_runtime.h>
#include <hip/hip_bf16.h>

typedef __bf16 bf16;
typedef __bf16 bf16x8 __attribute__((ext_vector_type(8)));
typedef float floatx4 __attribute__((ext_vector_type(4)));
typedef float floatx2 __attribute__((ext_vector_type(2)));
typedef unsigned int uint;
typedef uint uintx4 __attribute__((ext_vector_type(4)));
typedef unsigned long long u64;
typedef __attribute__((address_space(1))) void gvoid;
typedef __attribute__((address_space(3))) void lvoid;

#define MFMA16(a, b, c) __builtin_amdgcn_mfma_f32_16x16x32_bf16((a), (b), (c), 0, 0, 0)
#define NB_REC 64

__global__ void k_cvt(const float* __restrict__ src, bf16* __restrict__ dst, int n) {
    int idx = blockIdx.x * 256 + threadIdx.x;
    if (idx < n) dst[idx] = (bf16)src[idx];
}

// Transpose fp32 (B,T,D) -> (t*32+b, D) bf16; zero the tagged-exchange buffer
// (2 slots x 32x1024 fp32). Tag 0 never validates, so zeroing per replay makes
// the flagless protocol safe against stale end-states from a previous replay.
__global__ void k_prep(const float* __restrict__ inp, bf16* __restrict__ xT,
                       float* __restrict__ exch) {
    size_t idx = (size_t)blockIdx.x * 256 + threadIdx.x;
    if (idx < 2 * 32 * 1024) exch[idx] = 0.f;
    int d = (int)(idx & 255);
    int t = (int)((idx >> 8) & 511);
    int b = (int)(idx >> 17);
    xT[((size_t)(t * 32 + b) << 8) | d] = (bf16)inp[idx];
}

__global__ void k_movmean(const bf16* __restrict__ xT, bf16* __restrict__ out,
                          int s) {
    size_t idx = (size_t)blockIdx.x * 256 + threadIdx.x;
    int d = (int)(idx & 255);
    int m = (int)(idx >> 8);
    int t = m >> 5, b = m & 31;
    float acc = 0.f;
    for (int i = 0; i < s; ++i)
        acc += (float)xT[(((size_t)(t + i) * 32 + b) << 8) | d];
    out[idx] = (bf16)(acc * (1.f / (float)s));
}

// ---------------------------------------------------------------------------
// Tiled MFMA GEMM, 128x128 tile, BK=64, global_load_lds(16B) staging with
// XOR chunk swizzle (chunk q of row m at q^(m&7)). C = A1·W1^T (+ A2·W2^T)
// + biases (fp32). Cf!=null: fp32 out; else bf16 Cb. Stores guarded (Mstore).
// ---------------------------------------------------------------------------
__global__ __launch_bounds__(256, 2) void k_gemm(
    const bf16* __restrict__ A1, int lda1, const bf16* __restrict__ W1, int nk1,
    const bf16* __restrict__ A2, int lda2, const bf16* __restrict__ W2, int nk2,
    const float* __restrict__ bias1, const float* __restrict__ bias2,
    float* __restrict__ Cf, bf16* __restrict__ Cb, int ldc, int Mstore) {
    __shared__ bf16 lsA[128 * 64];
    __shared__ bf16 lsW[128 * 64];
    const int tid = threadIdx.x;
    const int lane = tid & 63, w = tid >> 6;
    const int quad = lane >> 4, lr = lane & 15;
    const int wm = w >> 1, wn = w & 1;
    const int m0 = blockIdx.y * 128, n0 = blockIdx.x * 128;

    floatx4 acc[4][4] = {};

    const bf16* As[2] = {A1, A2};
    const bf16* Ws[2] = {W1, W2};
    const int ldas[2] = {lda1, lda2};
    const int nks[2] = {nk1, nk2};

    for (int ph = 0; ph < 2; ++ph) {
        const int nk = nks[ph];
        if (nk == 0) continue;
        const bf16* A = As[ph];
        const bf16* Wp = Ws[ph];
        const int lda = ldas[ph];
        const int ldw = nk * 64;
        for (int kb = 0; kb < nk; ++kb) {
            const bf16* Ab = A + (size_t)m0 * lda + (size_t)kb * 64;
            const bf16* Wb = Wp + (size_t)n0 * ldw + (size_t)kb * 64;
#pragma unroll
            for (int i = 0; i < 4; ++i) {
                int c = (i * 4 + w) * 64 + lane;
                int m = c >> 3, q = c & 7;
                const bf16* g1 = Ab + (size_t)m * lda + ((q ^ (m & 7)) << 3);
                __builtin_amdgcn_global_load_lds((const gvoid*)g1,
                                                 (lvoid*)(lsA + (i * 4 + w) * 512), 16, 0, 0);
                const bf16* g2 = Wb + (size_t)m * ldw + ((q ^ (m & 7)) << 3);
                __builtin_amdgcn_global_load_lds((const gvoid*)g2,
                                                 (lvoid*)(lsW + (i * 4 + w) * 512), 16, 0, 0);
            }
            __syncthreads();
#pragma unroll
            for (int s = 0; s < 2; ++s) {
                bf16x8 af[4], bfr[4];
#pragma unroll
                for (int i = 0; i < 4; ++i) {
                    int kc = s * 4 + quad;
                    int m = wm * 64 + i * 16 + lr;
                    af[i] = *(const bf16x8*)(lsA + m * 64 + ((kc ^ (m & 7)) << 3));
                    int n = wn * 64 + i * 16 + lr;
                    bfr[i] = *(const bf16x8*)(lsW + n * 64 + ((kc ^ (n & 7)) << 3));
                }
#pragma unroll
                for (int i = 0; i < 4; ++i)
#pragma unroll
                    for (int j = 0; j < 4; ++j)
                        acc[i][j] = MFMA16(af[i], bfr[j], acc[i][j]);
            }
            __syncthreads();
        }
    }

    // Epilogue (C/D layout: col = lane&15, row = quad*4 + reg).
#pragma unroll
    for (int j = 0; j < 4; ++j) {
        int col = n0 + wn * 64 + j * 16 + lr;
        float bs = 0.f;
        if (bias1) bs += bias1[col];
        if (bias2) bs += bias2[col];
#pragma unroll
        for (int i = 0; i < 4; ++i) {
            int rowb = m0 + wm * 64 + i * 16 + quad * 4;
#pragma unroll
            for (int r = 0; r < 4; ++r) {
                int row = rowb + r;
                if (row < Mstore) {
                    float v = acc[i][j][r] + bs;
                    if (Cf) Cf[(size_t)row * ldc + col] = v;
                    else    Cb[(size_t)row * ldc + col] = (bf16)v;
                }
            }
        }
    }
}

// Pack a tagged-fp32 pair (u64) into a bf16 pair (u32), RNE.
__device__ __forceinline__ uint pkbf(u64 wv) {
    union { float f; uint u; } a, b;
    a.u = (uint)wv;
    b.u = (uint)(wv >> 32);
    union { bf16 h[2]; uint u; } pk;
    pk.h[0] = (bf16)a.f;
    pk.h[1] = (bf16)b.f;
    return pk.u;
}

// ---------------------------------------------------------------------------
// Persistent GRU recurrence, flagless tagged-exchange protocol.
// 64 blocks x 384 threads (6 waves = 2 Mtiles x 3 gates). Block blk owns
// hidden cols [blk*16,+16).
//
// Cross-block h exchange: state S lives in exch slot (S&1) as 32x1024 fp32
// whose low-3 mantissa bits hold tag(S) = 1+(S%7). Producers fire relaxed
// sc1 stores and proceed (NO vmcnt ack, NO flag, NO grid barrier). Consumers
// speculatively load the slot (sc1, L1/L2-bypass), validate every 4B word's
// tag, and retry only stale chunks -> one L3 hop of latency instead of three
// (store-ack, flag-visible, poll). Slot-reuse safety: writing state S
// requires having staged S-1, which requires all blocks stored S-1, which
// requires they finished reading slot (S-1)&1 = (S+1)&1. Tags differ for
// S vs S-2 (2 % 7 != 0). k_prep zeroes the buffer each replay (tag 0 never
// valid). Blocks may drift; data deps self-synchronize.
//
// Per step: stage(validate+cvt->LDS, swizzled) | sync | MFMA (dual acc) |
// sync | gh exchange (aliases hT) | sync | gates + tagged store + outs |
// sync. G rows prefetched one step ahead.
// LDS: Whh slice 48x1024 swizzled (96KB) + h tile (64KB) = 160KB.
// ---------------------------------------------------------------------------
__global__ __launch_bounds__(384, 1) void k_rec(
    const float* __restrict__ G, const bf16* __restrict__ Whh,
    const float* __restrict__ bhh, bf16* __restrict__ outs,
    float* __restrict__ exch, float* __restrict__ hf,
    float* __restrict__ hid_out,
    int T, int init, int final_, uint sbase) {
    const int tid = threadIdx.x, blk = blockIdx.x;
    const int lane = tid & 63, w = tid >> 6;
    const int quad = lane >> 4, lr = lane & 15;
    const int mi = (w >= 3) ? 1 : 0, ni = w - mi * 3;
    const int sxor = lr & 7;

    __shared__ __attribute__((aligned(16))) char smem[163840];
    bf16* lw = (bf16*)smem;              // 48 rows x 128 chunks (swizzled), 96KB
    bf16* hT = (bf16*)(smem + 98304);    // 32 rows x 128 chunks (swizzled), 64KB
    float* gh = (float*)(smem + 98304);  // alias of hT: 96 x 17 fp32 (6528B)

    // Whh slice -> LDS, swizzled: chunk q of row n stored at q ^ (n&7).
    for (int c = tid; c < 48 * 128; c += 384) {
        int row = c >> 7, q = c & 127;
        int grow = (row >> 4) * 1024 + blk * 16 + (row & 15);
        *(bf16x8*)(lw + row * 1024 + (((q ^ (row & 7)) << 3))) =
            *(const bf16x8*)(Whh + (size_t)grow * 1024 + q * 8);
    }

    // Elementwise mapping: thread (tid<256) owns batch row eb, col pair ec.
    const int eb = tid >> 3;
    const int ec = (tid & 7) * 2;
    const int ecg = blk * 16 + ec;

    float bhr0 = 0.f, bhr1 = 0.f, bhi0 = 0.f, bhi1 = 0.f, bhn0 = 0.f, bhn1 = 0.f;
    float hreg0 = 0.f, hreg1 = 0.f;
    if (tid < 256) {
        bhr0 = bhh[ecg];        bhr1 = bhh[ecg + 1];
        bhi0 = bhh[1024 + ecg]; bhi1 = bhh[1024 + ecg + 1];
        bhn0 = bhh[2048 + ecg]; bhn1 = bhh[2048 + ecg + 1];
        if (!init) {
            floatx2 h = *(const floatx2*)(hf + (size_t)eb * 1024 + ecg);
            hreg0 = h.x;
            hreg1 = h.y;
        }
        // Publish initial state sbase (tagged).
        uint tg = 1u + (sbase % 7u);
        uint w0 = (__float_as_uint(hreg0) & ~7u) | tg;
        uint w1 = (__float_as_uint(hreg1) & ~7u) | tg;
        u64 pkd = (u64)w0 | ((u64)w1 << 32);
        __hip_atomic_store((u64*)(exch + ((sbase & 1u) << 15) + eb * 1024 + ecg),
                           pkd, __ATOMIC_RELAXED, __HIP_MEMORY_SCOPE_AGENT);
    }

    // G prefetch registers: pA = current step, pB = next step.
    floatx2 pAr, pAi, pAn, pBr, pBi, pBn;
    if (tid < 256) {
        const float* Grow = G + (size_t)eb * 3072 + ecg;
        pAr = *(const floatx2*)(Grow);
        pAi = *(const floatx2*)(Grow + 1024);
        pAn = *(const floatx2*)(Grow + 2048);
    }

    uint S = sbase;
    for (int t = 0; t < T; ++t) {
        // --- Stage state S: validate tags, convert, swizzled write to LDS --
        {
            const u64* sbp = (const u64*)(exch + ((S & 1u) << 15));
            const uint tg = 1u + (S % 7u);
            const u64 tagpat = (u64)tg | ((u64)tg << 32);
            const u64 SEVEN = 0x0000000700000007ull;
            u64 d0[11], d1[11], d2[11], d3[11];
            uint mask = (tid < 256) ? 0x7FFu : 0x3FFu;
            while (mask) {
                uint m = mask;
#pragma unroll
                for (int r = 0; r < 11; ++r) {
                    if (m & (1u << r)) {
                        const u64* p = sbp + ((size_t)(tid + r * 384) << 2);
                        d0[r] = __hip_atomic_load(p + 0, __ATOMIC_RELAXED, __HIP_MEMORY_SCOPE_AGENT);
                        d1[r] = __hip_atomic_load(p + 1, __ATOMIC_RELAXED, __HIP_MEMORY_SCOPE_AGENT);
                        d2[r] = __hip_atomic_load(p + 2, __ATOMIC_RELAXED, __HIP_MEMORY_SCOPE_AGENT);
                        d3[r] = __hip_atomic_load(p + 3, __ATOMIC_RELAXED, __HIP_MEMORY_SCOPE_AGENT);
                    }
                }
#pragma unroll
                for (int r = 0; r < 11; ++r) {
                    if (m & (1u << r)) {
                        bool ok = ((d0[r] & SEVEN) == tagpat) &&
                                  ((d1[r] & SEVEN) == tagpat) &&
                                  ((d2[r] & SEVEN) == tagpat) &&
                                  ((d3[r] & SEVEN) == tagpat);
                        if (ok) {
                            int ci = tid + r * 384;
                            int row = ci >> 7, q = ci & 127;
                            uintx4 ov;
                            ov.x = pkbf(d0[r]);
                            ov.y = pkbf(d1[r]);
                            ov.z = pkbf(d2[r]);
                            ov.w = pkbf(d3[r]);
                            *(uintx4*)(hT + row * 1024 + ((q ^ (row & 7)) << 3)) = ov;
                            mask &= ~(1u << r);
                        }
                    }
                }
                if (mask) __builtin_amdgcn_s_sleep(1);
            }
        }
        __syncthreads();

        // --- MFMA: gh(partial) = h @ Whh_slice^T, fragments from LDS ------
        floatx4 acc0 = {0.f, 0.f, 0.f, 0.f}, acc1 = {0.f, 0.f, 0.f, 0.f};
        const bf16* aB = hT + (mi * 16 + lr) * 1024;
        const bf16* bB = lw + (ni * 16 + lr) * 1024;
#pragma unroll
        for (int kt = 0; kt < 32; kt += 2) {
            int c0 = quad + kt * 4;
            int c1 = c0 + 4;
            bf16x8 a0 = *(const bf16x8*)(aB + ((c0 ^ sxor) << 3));
            bf16x8 b0 = *(const bf16x8*)(bB + ((c0 ^ sxor) << 3));
            acc0 = MFMA16(a0, b0, acc0);
            bf16x8 a1 = *(const bf16x8*)(aB + ((c1 ^ sxor) << 3));
            bf16x8 b1 = *(const bf16x8*)(bB + ((c1 ^ sxor) << 3));
            acc1 = MFMA16(a1, b1, acc1);
        }
        floatx4 acc = acc0 + acc1;
        __syncthreads();  // all waves done READING hT before gh overwrites it

#pragma unroll
        for (int r = 0; r < 4; ++r)
            gh[(ni * 32 + mi * 16 + quad * 4 + r) * 17 + lr] = acc[r];
        __syncthreads();

        if (tid < 256) {
            // Next-step G loads first: latency hides under gate math and the
            // next staging round.
            if (t + 1 < T) {
                const float* Grow = G + ((size_t)(t + 1) * 32 + eb) * 3072 + ecg;
                pBr = *(const floatx2*)(Grow);
                pBi = *(const floatx2*)(Grow + 1024);
                pBn = *(const floatx2*)(Grow + 2048);
            }
            float ghr0 = gh[eb * 17 + ec]            + bhr0;
            float ghr1 = gh[eb * 17 + ec + 1]        + bhr1;
            float ghi0 = gh[(32 + eb) * 17 + ec]     + bhi0;
            float ghi1 = gh[(32 + eb) * 17 + ec + 1] + bhi1;
            float ghn0 = gh[(64 + eb) * 17 + ec]     + bhn0;
            float ghn1 = gh[(64 + eb) * 17 + ec + 1] + bhn1;
            float rg0 = 1.f / (1.f + __expf(-(pAr.x + ghr0)));
            float rg1 = 1.f / (1.f + __expf(-(pAr.y + ghr1)));
            float ig0 = 1.f / (1.f + __expf(-(pAi.x + ghi0)));
            float ig1 = 1.f / (1.f + __expf(-(pAi.y + ghi1)));
            float pre0 = pAn.x + rg0 * ghn0;
            float pre1 = pAn.y + rg1 * ghn1;
            float e20 = __expf(2.f * pre0);
            float e21 = __expf(2.f * pre1);
            float ng0 = 1.f - 2.f / (e20 + 1.f);  // tanh(pre)
            float ng1 = 1.f - 2.f / (e21 + 1.f);
            hreg0 = ng0 + ig0 * (hreg0 - ng0);
            hreg1 = ng1 + ig1 * (hreg1 - ng1);
            // Publish state S+1: tagged fp32 pair, fire-and-forget.
            uint tgn = 1u + ((S + 1u) % 7u);
            uint w0 = (__float_as_uint(hreg0) & ~7u) | tgn;
            uint w1 = (__float_as_uint(hreg1) & ~7u) | tgn;
            u64 pkd = (u64)w0 | ((u64)w1 << 32);
            __hip_atomic_store((u64*)(exch + (((S + 1u) & 1u) << 15) + eb * 1024 + ecg),
                               pkd, __ATOMIC_RELAXED, __HIP_MEMORY_SCOPE_AGENT);
            union { bf16 h[2]; uint u; } pk;
            pk.h[0] = (bf16)hreg0;
            pk.h[1] = (bf16)hreg1;
            *(uint*)(outs + ((size_t)t * 32 + eb) * 1024 + ecg) = pk.u;
        }
        __syncthreads();  // gates done reading gh before next staging writes hT

        S++;
        pAr = pBr; pAi = pBi; pAn = pBn;
    }

    if (tid < 256) {
        floatx2 h;
        h.x = hreg0;
        h.y = hreg1;
        *(floatx2*)(hf + (size_t)eb * 1024 + ecg) = h;
        if (final_)
            *(floatx2*)(hid_out + (size_t)eb * 1024 + ecg) = h;
    }
}

// ---------------------------------------------------------------------------
extern "C" void kernel_launch(void* const* d_in, const int* in_sizes, int n_in,
                              void* d_out, int out_size, void* d_ws, size_t ws_size,
                              hipStream_t stream) {
    const float* inp  = (const float*)d_in[0];
    const float* Wxh0 = (const float*)d_in[1];
    const float* bxh0 = (const float*)d_in[2];
    const float* Whh0 = (const float*)d_in[3];
    const float* bhh0 = (const float*)d_in[4];
    const float* Wnh0 = (const float*)d_in[5];
    const float* bnh0 = (const float*)d_in[6];
    const float* Wxh1 = (const float*)d_in[7];
    const float* bxh1 = (const float*)d_in[8];
    const float* Whh1 = (const float*)d_in[9];
    const float* bhh1 = (const float*)d_in[10];
    const float* Wnh1 = (const float*)d_in[11];
    const float* bnh1 = (const float*)d_in[12];
    const float* Wxh2 = (const float*)d_in[13];
    const float* bxh2 = (const float*)d_in[14];
    const float* Whh2 = (const float*)d_in[15];
    const float* bhh2 = (const float*)d_in[16];
    const float* Wnh2 = (const float*)d_in[17];
    const float* bnh2 = (const float*)d_in[18];
    const float* Wout = (const float*)d_in[19];
    const float* bout = (const float*)d_in[20];
    float* out = (float*)d_out;  // reference output dtype is float32

    char* ws = (char*)d_ws;
    size_t o = 0;
    auto take = [&](size_t bytes) {
        o = (o + 255) & ~(size_t)255;
        char* p = ws + o;
        o += bytes;
        return p;
    };
    const size_t RP = 16512;  // row padding: covers GEMM A-tile overread
    bf16* xT    = (bf16*)take(RP * 256 * 2);
    bf16* ms1   = (bf16*)take(RP * 256 * 2);
    bf16* ms2   = (bf16*)take(RP * 256 * 2);
    bf16* outs0 = (bf16*)take(RP * 1024 * 2);
    bf16* outs1 = (bf16*)take(RP * 1024 * 2);
    bf16* outs2 = outs0;  // alias: outs0 dead after proj0 (launched first)
    float* exch = (float*)take((size_t)2 * 32 * 1024 * 4);  // tagged h exchange
    float* hf   = (float*)take((size_t)32 * 1024 * 4);
    bf16* wXh = (bf16*)take((size_t)3072 * 1024 * 2);
    bf16* wNh = (bf16*)take((size_t)3072 * 256 * 2);
    bf16* wHh = (bf16*)take((size_t)3072 * 1024 * 2);
    bf16* wOut = (bf16*)take((size_t)256 * 1024 * 2);
    o = (o + 255) & ~(size_t)255;

    size_t avail = (ws_size > o) ? (ws_size - o) : 0;
    int CT = (int)(avail / ((size_t)32 * 3072 * 4));
    if (CT > 512) CT = 512;
    if (CT < 4) CT = 4;
    float* G = (float*)(ws + o);
    (void)in_sizes; (void)n_in; (void)out_size;

    const size_t o0 = 0, o1 = (size_t)512 * 32 * 256, o2 = o1 + (size_t)511 * 32 * 256;
    const size_t ohid = o2 + (size_t)509 * 32 * 256;

    auto cvt = [&](const float* s, bf16* d, int n) {
        k_cvt<<<(n + 255) / 256, 256, 0, stream>>>(s, d, n);
    };
    cvt(Wout, wOut, 256 * 1024);
    k_prep<<<16384, 256, 0, stream>>>(inp, xT, exch);
    k_movmean<<<511 * 32, 256, 0, stream>>>(xT, ms1, 2);
    k_movmean<<<509 * 32, 256, 0, stream>>>(xT, ms2, 4);

    uint gstate = 0;  // monotonic state id across all layers/launches

    auto run_layer = [&](const bf16* xs, int ldx, const float* Wxh, int nkx,
                         const bf16* ms, const float* Wnh,
                         const float* bxh, const float* bnh,
                         const float* Whh, const float* bhh,
                         bf16* outs, float* hid, int T, int layer) {
        cvt(Wxh, wXh, 3072 * nkx * 64);
        cvt(Wnh, wNh, 3072 * 256);
        cvt(Whh, wHh, 3072 * 1024);
        for (int t0 = 0; t0 < T; t0 += CT) {
            int ct = (T - t0 < CT) ? (T - t0) : CT;
            int gy = (ct * 32 + 127) / 128;
            k_gemm<<<dim3(24, gy), 256, 0, stream>>>(
                xs + (size_t)t0 * 32 * ldx, ldx, wXh, nkx,
                ms + (size_t)t0 * 32 * 256, 256, wNh, 4,
                bxh, bnh, G, (bf16*)nullptr, 3072, ct * 32);
            k_rec<<<NB_REC, 384, 0, stream>>>(
                G, wHh, bhh, outs + (size_t)t0 * 32 * 1024, exch, hf, hid,
                ct, (t0 == 0) ? 1 : 0, (t0 + ct >= T) ? 1 : 0, gstate);
            gstate += (uint)ct + 1;
        }
        (void)layer;
    };

    // Layer 0 (ms0 == x): G = x@Wxh0^T + x@Wnh0^T + bxh0 + bnh0
    run_layer(xT, 256, Wxh0, 4, xT, Wnh0, bxh0, bnh0, Whh0, bhh0,
              outs0, out + ohid, 512, 0);
    // Layer 1: xs = outs0[1:], ms = ms1
    run_layer(outs0 + (size_t)32 * 1024, 1024, Wxh1, 16, ms1, Wnh1,
              bxh1, bnh1, Whh1, bhh1, outs1, out + ohid + 32768, 511, 1);
    // Projection of layer-0 outs BEFORE layer 2 overwrites the aliased buffer.
    k_gemm<<<dim3(2, 128), 256, 0, stream>>>(outs0, 1024, wOut, 16,
                                             nullptr, 0, nullptr, 0, bout, nullptr,
                                             out + o0, nullptr, 256, 16384);
    // Layer 2: xs = outs1[2:], ms = ms2; outs2 aliases outs0.
    run_layer(outs1 + (size_t)64 * 1024, 1024, Wxh2, 16, ms2, Wnh2,
              bxh2, bnh2, Whh2, bhh2, outs2, out + ohid + 65536, 509, 2);

    k_gemm<<<dim3(2, 128), 256, 0, stream>>>(outs1, 1024, wOut, 16,
                                             nullptr, 0, nullptr, 0, bout, nullptr,
                                             out + o1, nullptr, 256, 16352);
    k_gemm<<<dim3(2, 128), 256, 0, stream>>>(outs2, 1024, wOut, 16,
                                             nullptr, 0, nullptr, 0, bout, nullptr,
                                             out + o2, nullptr, 256, 16288);
}

// Round 6
// 6824.879 us; speedup vs baseline: 2.2036x; 2.2036x over previous
//
#include <hip/hip_runtime.h>
#include <hip/hip_bf16.h>

typedef __bf16 bf16;
typedef __bf16 bf16x8 __attribute__((ext_vector_type(8)));
typedef float floatx4 __attribute__((ext_vector_type(4)));
typedef float floatx2 __attribute__((ext_vector_type(2)));
typedef unsigned int uint;
typedef uint uintx4 __attribute__((ext_vector_type(4)));
typedef unsigned long long u64;
typedef u64 u64x2 __attribute__((ext_vector_type(2)));
typedef __attribute__((address_space(1))) void gvoid;
typedef __attribute__((address_space(3))) void lvoid;

#define MFMA16(a, b, c) __builtin_amdgcn_mfma_f32_16x16x32_bf16((a), (b), (c), 0, 0, 0)
#define NB_REC 64
#define FLAG_STRIDE 32  // uints per flag line (128B) to avoid false sharing

__global__ void k_cvt(const float* __restrict__ src, bf16* __restrict__ dst, int n) {
    int idx = blockIdx.x * 256 + threadIdx.x;
    if (idx < n) dst[idx] = (bf16)src[idx];
}

// Transpose fp32 (B,T,D) -> (t*32+b, D) bf16; zero 3 flag regions.
__global__ void k_prep(const float* __restrict__ inp, bf16* __restrict__ xT,
                       uint* __restrict__ bar) {
    size_t idx = (size_t)blockIdx.x * 256 + threadIdx.x;
    if (blockIdx.x == 0) {
        for (int i = threadIdx.x; i < 3 * NB_REC * FLAG_STRIDE; i += 256) bar[i] = 0;
    }
    int d = (int)(idx & 255);
    int t = (int)((idx >> 8) & 511);
    int b = (int)(idx >> 17);
    xT[((size_t)(t * 32 + b) << 8) | d] = (bf16)inp[idx];
}

__global__ void k_movmean(const bf16* __restrict__ xT, bf16* __restrict__ out,
                          int s) {
    size_t idx = (size_t)blockIdx.x * 256 + threadIdx.x;
    int d = (int)(idx & 255);
    int m = (int)(idx >> 8);
    int t = m >> 5, b = m & 31;
    float acc = 0.f;
    for (int i = 0; i < s; ++i)
        acc += (float)xT[(((size_t)(t + i) * 32 + b) << 8) | d];
    out[idx] = (bf16)(acc * (1.f / (float)s));
}

// ---------------------------------------------------------------------------
// Tiled MFMA GEMM, 128x128 tile, BK=64, global_load_lds(16B) staging with
// XOR chunk swizzle (chunk q of row m at q^(m&7)). C = A1·W1^T (+ A2·W2^T)
// + biases (fp32). Cf!=null: fp32 out; else bf16 Cb. Stores guarded (Mstore).
// ---------------------------------------------------------------------------
__global__ __launch_bounds__(256, 2) void k_gemm(
    const bf16* __restrict__ A1, int lda1, const bf16* __restrict__ W1, int nk1,
    const bf16* __restrict__ A2, int lda2, const bf16* __restrict__ W2, int nk2,
    const float* __restrict__ bias1, const float* __restrict__ bias2,
    float* __restrict__ Cf, bf16* __restrict__ Cb, int ldc, int Mstore) {
    __shared__ bf16 lsA[128 * 64];
    __shared__ bf16 lsW[128 * 64];
    const int tid = threadIdx.x;
    const int lane = tid & 63, w = tid >> 6;
    const int quad = lane >> 4, lr = lane & 15;
    const int wm = w >> 1, wn = w & 1;
    const int m0 = blockIdx.y * 128, n0 = blockIdx.x * 128;

    floatx4 acc[4][4] = {};

    const bf16* As[2] = {A1, A2};
    const bf16* Ws[2] = {W1, W2};
    const int ldas[2] = {lda1, lda2};
    const int nks[2] = {nk1, nk2};

    for (int ph = 0; ph < 2; ++ph) {
        const int nk = nks[ph];
        if (nk == 0) continue;
        const bf16* A = As[ph];
        const bf16* Wp = Ws[ph];
        const int lda = ldas[ph];
        const int ldw = nk * 64;
        for (int kb = 0; kb < nk; ++kb) {
            const bf16* Ab = A + (size_t)m0 * lda + (size_t)kb * 64;
            const bf16* Wb = Wp + (size_t)n0 * ldw + (size_t)kb * 64;
#pragma unroll
            for (int i = 0; i < 4; ++i) {
                int c = (i * 4 + w) * 64 + lane;
                int m = c >> 3, q = c & 7;
                const bf16* g1 = Ab + (size_t)m * lda + ((q ^ (m & 7)) << 3);
                __builtin_amdgcn_global_load_lds((const gvoid*)g1,
                                                 (lvoid*)(lsA + (i * 4 + w) * 512), 16, 0, 0);
                const bf16* g2 = Wb + (size_t)m * ldw + ((q ^ (m & 7)) << 3);
                __builtin_amdgcn_global_load_lds((const gvoid*)g2,
                                                 (lvoid*)(lsW + (i * 4 + w) * 512), 16, 0, 0);
            }
            __syncthreads();
#pragma unroll
            for (int s = 0; s < 2; ++s) {
                bf16x8 af[4], bfr[4];
#pragma unroll
                for (int i = 0; i < 4; ++i) {
                    int kc = s * 4 + quad;
                    int m = wm * 64 + i * 16 + lr;
                    af[i] = *(const bf16x8*)(lsA + m * 64 + ((kc ^ (m & 7)) << 3));
                    int n = wn * 64 + i * 16 + lr;
                    bfr[i] = *(const bf16x8*)(lsW + n * 64 + ((kc ^ (n & 7)) << 3));
                }
#pragma unroll
                for (int i = 0; i < 4; ++i)
#pragma unroll
                    for (int j = 0; j < 4; ++j)
                        acc[i][j] = MFMA16(af[i], bfr[j], acc[i][j]);
            }
            __syncthreads();
        }
    }

    // Epilogue (C/D layout: col = lane&15, row = quad*4 + reg).
#pragma unroll
    for (int j = 0; j < 4; ++j) {
        int col = n0 + wn * 64 + j * 16 + lr;
        float bs = 0.f;
        if (bias1) bs += bias1[col];
        if (bias2) bs += bias2[col];
#pragma unroll
        for (int i = 0; i < 4; ++i) {
            int rowb = m0 + wm * 64 + i * 16 + quad * 4;
#pragma unroll
            for (int r = 0; r < 4; ++r) {
                int row = rowb + r;
                if (row < Mstore) {
                    float v = acc[i][j][r] + bs;
                    if (Cf) Cf[(size_t)row * ldc + col] = v;
                    else    Cb[(size_t)row * ldc + col] = (bf16)v;
                }
            }
        }
    }
}

// ---------------------------------------------------------------------------
// Persistent GRU recurrence over a chunk of T steps. 64 blocks x 384 threads
// (6 waves = 2 Mtiles x 3 gates). Block blk owns hidden cols [blk*16,+16).
//
// Round-2-proven protocol. Per step:
//   1. Stage full h tile (32x1024 bf16 = 64KB) global->LDS with independent
//      sc1 (agent-scope, L1/L2-bypass) loads, issue-all then write-all, into
//      an XOR-chunk-swizzled layout (chunk q of row m at q^(m&7)).
//   2. 6 MFMA waves read h + Whh fragments from LDS (dual accumulators).
//   3. gh exchange buffer ALIASES the h tile region (time-disjoint).
//   4. Gates; h publish = packed 4B sc1 store; sync (drains ONLY the 1KB h
//      publish); flag store; THEN deferred traffic (next-step G prefetch +
//      outs HBM store) whose latency drains under the poll window instead of
//      delaying the flag release; lane-parallel flag poll; sync.
// LDS: Whh slice 48x1024 swizzled (96KB) + h tile (64KB) = 160KB exactly.
// bhh lives in registers.
// ---------------------------------------------------------------------------
__global__ __launch_bounds__(384, 1) void k_rec(
    const float* __restrict__ G, const bf16* __restrict__ Whh,
    const float* __restrict__ bhh, bf16* __restrict__ outs,
    bf16* __restrict__ h01, float* __restrict__ hf,
    float* __restrict__ hid_out, uint* __restrict__ bar,
    int T, int init, int final_, uint tgt0) {
    const int tid = threadIdx.x, blk = blockIdx.x;
    const int lane = tid & 63, w = tid >> 6;
    const int quad = lane >> 4, lr = lane & 15;
    const int mi = (w >= 3) ? 1 : 0, ni = w - mi * 3;
    const int sxor = lr & 7;

    __shared__ __attribute__((aligned(16))) char smem[163840];
    bf16* lw = (bf16*)smem;              // 48 rows x 128 chunks (swizzled), 96KB
    bf16* hT = (bf16*)(smem + 98304);    // 32 rows x 128 chunks (swizzled), 64KB
    float* gh = (float*)(smem + 98304);  // alias of hT: 96 x 17 fp32 (6528B)

    // Whh slice -> LDS, swizzled: chunk q of row n stored at q ^ (n&7).
    for (int c = tid; c < 48 * 128; c += 384) {
        int row = c >> 7, q = c & 127;
        int grow = (row >> 4) * 1024 + blk * 16 + (row & 15);
        *(bf16x8*)(lw + row * 1024 + (((q ^ (row & 7)) << 3))) =
            *(const bf16x8*)(Whh + (size_t)grow * 1024 + q * 8);
    }

    // Elementwise mapping: thread (tid<256) owns batch row eb, col pair ec.
    const int eb = tid >> 3;
    const int ec = (tid & 7) * 2;
    const int ecg = blk * 16 + ec;

    float bhr0 = 0.f, bhr1 = 0.f, bhi0 = 0.f, bhi1 = 0.f, bhn0 = 0.f, bhn1 = 0.f;
    float hreg0 = 0.f, hreg1 = 0.f;
    if (tid < 256) {
        bhr0 = bhh[ecg];        bhr1 = bhh[ecg + 1];
        bhi0 = bhh[1024 + ecg]; bhi1 = bhh[1024 + ecg + 1];
        bhn0 = bhh[2048 + ecg]; bhn1 = bhh[2048 + ecg + 1];
        if (!init) {
            floatx2 h = *(const floatx2*)(hf + (size_t)eb * 1024 + ecg);
            hreg0 = h.x;
            hreg1 = h.y;
        }
        union { bf16 h[2]; uint u; } pk;
        pk.h[0] = (bf16)hreg0;
        pk.h[1] = (bf16)hreg1;
        __hip_atomic_store((uint*)(h01 + (size_t)eb * 1024 + ecg), pk.u,
                           __ATOMIC_RELAXED, __HIP_MEMORY_SCOPE_AGENT);
    }

    // G prefetch registers: pA = current step, pB = next step.
    floatx2 pAr, pAi, pAn, pBr, pBi, pBn;
    if (tid < 256) {
        const float* Grow = G + (size_t)eb * 3072 + ecg;
        pAr = *(const floatx2*)(Grow);
        pAi = *(const floatx2*)(Grow + 1024);
        pAn = *(const floatx2*)(Grow + 2048);
    }

    uint* myflag = bar + (uint)blk * FLAG_STRIDE;

    __syncthreads();  // drains h01 sc1 stores (vmcnt(0) before s_barrier)
    if (tid == 0)
        __hip_atomic_store(myflag, tgt0, __ATOMIC_RELAXED, __HIP_MEMORY_SCOPE_AGENT);
    if (tid < NB_REC) {
        const uint* fp = bar + (uint)tid * FLAG_STRIDE;
        while (__hip_atomic_load(fp, __ATOMIC_RELAXED, __HIP_MEMORY_SCOPE_AGENT) < tgt0)
            __builtin_amdgcn_s_sleep(1);
    }
    __syncthreads();

    for (int t = 0; t < T; ++t) {
        const bf16* hb = h01 + (size_t)(t & 1) * (32 * 1024);
        bf16* hn = h01 + (size_t)((t + 1) & 1) * (32 * 1024);

        // --- Stage h tile -> LDS (sc1 loads, issue-all then write-all) ----
        u64 s0[11], s1[11];
#pragma unroll
        for (int r = 0; r < 11; ++r) {
            int ci = tid + r * 384;
            if (r < 10 || ci < 4096) {
                const u64* src = (const u64*)(hb + (size_t)ci * 8);
                s0[r] = __hip_atomic_load(src, __ATOMIC_RELAXED, __HIP_MEMORY_SCOPE_AGENT);
                s1[r] = __hip_atomic_load(src + 1, __ATOMIC_RELAXED, __HIP_MEMORY_SCOPE_AGENT);
            }
        }
#pragma unroll
        for (int r = 0; r < 11; ++r) {
            int ci = tid + r * 384;
            if (r < 10 || ci < 4096) {
                int row = ci >> 7, q = ci & 127;
                u64x2 v;
                v.x = s0[r];
                v.y = s1[r];
                *(u64x2*)(hT + row * 1024 + ((q ^ (row & 7)) << 3)) = v;
            }
        }
        __syncthreads();

        // --- MFMA: gh(partial) = h @ Whh_slice^T, fragments from LDS ------
        floatx4 acc0 = {0.f, 0.f, 0.f, 0.f}, acc1 = {0.f, 0.f, 0.f, 0.f};
        const bf16* aB = hT + (mi * 16 + lr) * 1024;
        const bf16* bB = lw + (ni * 16 + lr) * 1024;
#pragma unroll
        for (int kt = 0; kt < 32; kt += 2) {
            int c0 = quad + kt * 4;
            int c1 = c0 + 4;
            bf16x8 a0 = *(const bf16x8*)(aB + ((c0 ^ sxor) << 3));
            bf16x8 b0 = *(const bf16x8*)(bB + ((c0 ^ sxor) << 3));
            acc0 = MFMA16(a0, b0, acc0);
            bf16x8 a1 = *(const bf16x8*)(aB + ((c1 ^ sxor) << 3));
            bf16x8 b1 = *(const bf16x8*)(bB + ((c1 ^ sxor) << 3));
            acc1 = MFMA16(a1, b1, acc1);
        }
        floatx4 acc = acc0 + acc1;
        __syncthreads();  // all waves done READING hT before gh overwrites it

#pragma unroll
        for (int r = 0; r < 4; ++r)
            gh[(ni * 32 + mi * 16 + quad * 4 + r) * 17 + lr] = acc[r];
        __syncthreads();

        uint pku = 0u;
        if (tid < 256) {
            float ghr0 = gh[eb * 17 + ec]            + bhr0;
            float ghr1 = gh[eb * 17 + ec + 1]        + bhr1;
            float ghi0 = gh[(32 + eb) * 17 + ec]     + bhi0;
            float ghi1 = gh[(32 + eb) * 17 + ec + 1] + bhi1;
            float ghn0 = gh[(64 + eb) * 17 + ec]     + bhn0;
            float ghn1 = gh[(64 + eb) * 17 + ec + 1] + bhn1;
            float rg0 = 1.f / (1.f + __expf(-(pAr.x + ghr0)));
            float rg1 = 1.f / (1.f + __expf(-(pAr.y + ghr1)));
            float ig0 = 1.f / (1.f + __expf(-(pAi.x + ghi0)));
            float ig1 = 1.f / (1.f + __expf(-(pAi.y + ghi1)));
            float pre0 = pAn.x + rg0 * ghn0;
            float pre1 = pAn.y + rg1 * ghn1;
            float e20 = __expf(2.f * pre0);
            float e21 = __expf(2.f * pre1);
            float ng0 = 1.f - 2.f / (e20 + 1.f);  // tanh(pre)
            float ng1 = 1.f - 2.f / (e21 + 1.f);
            hreg0 = ng0 + ig0 * (hreg0 - ng0);
            hreg1 = ng1 + ig1 * (hreg1 - ng1);
            union { bf16 h[2]; uint u; } pk;
            pk.h[0] = (bf16)hreg0;
            pk.h[1] = (bf16)hreg1;
            pku = pk.u;
            // Publish h_{t+1} (sc1): the ONLY memory op the next sync drains.
            __hip_atomic_store((uint*)(hn + (size_t)eb * 1024 + ecg), pku,
                               __ATOMIC_RELAXED, __HIP_MEMORY_SCOPE_AGENT);
        }
        __syncthreads();  // drains just the 1KB h publish -> fast flag release

        uint tgt = tgt0 + 1 + (uint)t;
        if (tid == 0)
            __hip_atomic_store(myflag, tgt, __ATOMIC_RELAXED, __HIP_MEMORY_SCOPE_AGENT);

        // Deferred traffic: next-step G prefetch + outs store. Issued after
        // the flag so their latency drains under the poll window, not on the
        // flag-release path.
        if (tid < 256) {
            if (t + 1 < T) {
                const float* Grow = G + ((size_t)(t + 1) * 32 + eb) * 3072 + ecg;
                pBr = *(const floatx2*)(Grow);
                pBi = *(const floatx2*)(Grow + 1024);
                pBn = *(const floatx2*)(Grow + 2048);
            }
            *(uint*)(outs + ((size_t)t * 32 + eb) * 1024 + ecg) = pku;
        }
        if (t + 1 < T && tid < NB_REC) {
            const uint* fp = bar + (uint)tid * FLAG_STRIDE;
            while (__hip_atomic_load(fp, __ATOMIC_RELAXED, __HIP_MEMORY_SCOPE_AGENT) < tgt)
                __builtin_amdgcn_s_sleep(1);
        }
        __syncthreads();

        pAr = pBr; pAi = pBi; pAn = pBn;
    }

    if (tid < 256) {
        floatx2 h;
        h.x = hreg0;
        h.y = hreg1;
        *(floatx2*)(hf + (size_t)eb * 1024 + ecg) = h;
        if (final_)
            *(floatx2*)(hid_out + (size_t)eb * 1024 + ecg) = h;
    }
}

// ---------------------------------------------------------------------------
extern "C" void kernel_launch(void* const* d_in, const int* in_sizes, int n_in,
                              void* d_out, int out_size, void* d_ws, size_t ws_size,
                              hipStream_t stream) {
    const float* inp  = (const float*)d_in[0];
    const float* Wxh0 = (const float*)d_in[1];
    const float* bxh0 = (const float*)d_in[2];
    const float* Whh0 = (const float*)d_in[3];
    const float* bhh0 = (const float*)d_in[4];
    const float* Wnh0 = (const float*)d_in[5];
    const float* bnh0 = (const float*)d_in[6];
    const float* Wxh1 = (const float*)d_in[7];
    const float* bxh1 = (const float*)d_in[8];
    const float* Whh1 = (const float*)d_in[9];
    const float* bhh1 = (const float*)d_in[10];
    const float* Wnh1 = (const float*)d_in[11];
    const float* bnh1 = (const float*)d_in[12];
    const float* Wxh2 = (const float*)d_in[13];
    const float* bxh2 = (const float*)d_in[14];
    const float* Whh2 = (const float*)d_in[15];
    const float* bhh2 = (const float*)d_in[16];
    const float* Wnh2 = (const float*)d_in[17];
    const float* bnh2 = (const float*)d_in[18];
    const float* Wout = (const float*)d_in[19];
    const float* bout = (const float*)d_in[20];
    float* out = (float*)d_out;  // reference output dtype is float32

    char* ws = (char*)d_ws;
    size_t o = 0;
    auto take = [&](size_t bytes) {
        o = (o + 255) & ~(size_t)255;
        char* p = ws + o;
        o += bytes;
        return p;
    };
    const size_t RP = 16512;  // row padding: covers GEMM A-tile overread
    bf16* xT    = (bf16*)take(RP * 256 * 2);
    bf16* ms1   = (bf16*)take(RP * 256 * 2);
    bf16* ms2   = (bf16*)take(RP * 256 * 2);
    bf16* outs0 = (bf16*)take(RP * 1024 * 2);
    bf16* outs1 = (bf16*)take(RP * 1024 * 2);
    bf16* outs2 = outs0;  // alias: outs0 dead after proj0 (launched first)
    bf16* h01   = (bf16*)take((size_t)2 * 32 * 1024 * 2);
    float* hf   = (float*)take((size_t)32 * 1024 * 4);
    uint* bar   = (uint*)take((size_t)3 * NB_REC * FLAG_STRIDE * 4);
    bf16* wXh = (bf16*)take((size_t)3072 * 1024 * 2);
    bf16* wNh = (bf16*)take((size_t)3072 * 256 * 2);
    bf16* wHh = (bf16*)take((size_t)3072 * 1024 * 2);
    bf16* wOut = (bf16*)take((size_t)256 * 1024 * 2);
    o = (o + 255) & ~(size_t)255;

    size_t avail = (ws_size > o) ? (ws_size - o) : 0;
    int CT = (int)(avail / ((size_t)32 * 3072 * 4));
    if (CT > 512) CT = 512;
    if (CT < 4) CT = 4;
    float* G = (float*)(ws + o);
    (void)in_sizes; (void)n_in; (void)out_size;

    const size_t o0 = 0, o1 = (size_t)512 * 32 * 256, o2 = o1 + (size_t)511 * 32 * 256;
    const size_t ohid = o2 + (size_t)509 * 32 * 256;

    auto cvt = [&](const float* s, bf16* d, int n) {
        k_cvt<<<(n + 255) / 256, 256, 0, stream>>>(s, d, n);
    };
    cvt(Wout, wOut, 256 * 1024);
    k_prep<<<16384, 256, 0, stream>>>(inp, xT, bar);
    k_movmean<<<511 * 32, 256, 0, stream>>>(xT, ms1, 2);
    k_movmean<<<509 * 32, 256, 0, stream>>>(xT, ms2, 4);

    auto run_layer = [&](const bf16* xs, int ldx, const float* Wxh, int nkx,
                         const bf16* ms, const float* Wnh,
                         const float* bxh, const float* bnh,
                         const float* Whh, const float* bhh,
                         bf16* outs, float* hid, int T, int layer) {
        cvt(Wxh, wXh, 3072 * nkx * 64);
        cvt(Wnh, wNh, 3072 * 256);
        cvt(Whh, wHh, 3072 * 1024);
        uint base = 0;
        for (int t0 = 0; t0 < T; t0 += CT) {
            int ct = (T - t0 < CT) ? (T - t0) : CT;
            int gy = (ct * 32 + 127) / 128;
            k_gemm<<<dim3(24, gy), 256, 0, stream>>>(
                xs + (size_t)t0 * 32 * ldx, ldx, wXh, nkx,
                ms + (size_t)t0 * 32 * 256, 256, wNh, 4,
                bxh, bnh, G, (bf16*)nullptr, 3072, ct * 32);
            k_rec<<<NB_REC, 384, 0, stream>>>(
                G, wHh, bhh, outs + (size_t)t0 * 32 * 1024, h01, hf, hid,
                bar + (size_t)NB_REC * FLAG_STRIDE * layer, ct,
                (t0 == 0) ? 1 : 0, (t0 + ct >= T) ? 1 : 0, base + 1);
            base += (uint)ct + 1;
        }
    };

    // Layer 0 (ms0 == x): G = x@Wxh0^T + x@Wnh0^T + bxh0 + bnh0
    run_layer(xT, 256, Wxh0, 4, xT, Wnh0, bxh0, bnh0, Whh0, bhh0,
              outs0, out + ohid, 512, 0);
    // Layer 1: xs = outs0[1:], ms = ms1
    run_layer(outs0 + (size_t)32 * 1024, 1024, Wxh1, 16, ms1, Wnh1,
              bxh1, bnh1, Whh1, bhh1, outs1, out + ohid + 32768, 511, 1);
    // Projection of layer-0 outs BEFORE layer 2 overwrites the aliased buffer.
    k_gemm<<<dim3(2, 128), 256, 0, stream>>>(outs0, 1024, wOut, 16,
                                             nullptr, 0, nullptr, 0, bout, nullptr,
                                             out + o0, nullptr, 256, 16384);
    // Layer 2: xs = outs1[2:], ms = ms2; outs2 aliases outs0.
    run_layer(outs1 + (size_t)64 * 1024, 1024, Wxh2, 16, ms2, Wnh2,
              bxh2, bnh2, Whh2, bhh2, outs2, out + ohid + 65536, 509, 2);

    k_gemm<<<dim3(2, 128), 256, 0, stream>>>(outs1, 1024, wOut, 16,
                                             nullptr, 0, nullptr, 0, bout, nullptr,
                                             out + o1, nullptr, 256, 16352);
    k_gemm<<<dim3(2, 128), 256, 0, stream>>>(outs2, 1024, wOut, 16,
                                             nullptr, 0, nullptr, 0, bout, nullptr,
                                             out + o2, nullptr, 256, 16288);
}

// Round 7
// 5464.369 us; speedup vs baseline: 2.7523x; 1.2490x over previous
//
#include <hip/hip_runtime.h>
#include <hip/hip_bf16.h>

typedef __bf16 bf16;
typedef __bf16 bf16x8 __attribute__((ext_vector_type(8)));
typedef float floatx4 __attribute__((ext_vector_type(4)));
typedef float floatx2 __attribute__((ext_vector_type(2)));
typedef unsigned int uint;
typedef uint uintx4 __attribute__((ext_vector_type(4)));
typedef unsigned long long u64;
typedef u64 u64x2 __attribute__((ext_vector_type(2)));
typedef __attribute__((address_space(1))) void gvoid;
typedef __attribute__((address_space(3))) void lvoid;

#define MFMA16(a, b, c) __builtin_amdgcn_mfma_f32_16x16x32_bf16((a), (b), (c), 0, 0, 0)
#define NB_REC 64
#define FLAG_STRIDE 32  // uints per flag line (128B) to avoid false sharing
#define HSTR 1040       // hT row stride in bf16: 2080B, 16B-aligned, group-balanced

__global__ void k_cvt(const float* __restrict__ src, bf16* __restrict__ dst, int n) {
    int idx = blockIdx.x * 256 + threadIdx.x;
    if (idx < n) dst[idx] = (bf16)src[idx];
}

// Transpose fp32 (B,T,D) -> (t*32+b, D) bf16; zero 3 flag regions.
__global__ void k_prep(const float* __restrict__ inp, bf16* __restrict__ xT,
                       uint* __restrict__ bar) {
    size_t idx = (size_t)blockIdx.x * 256 + threadIdx.x;
    if (blockIdx.x == 0) {
        for (int i = threadIdx.x; i < 3 * NB_REC * FLAG_STRIDE; i += 256) bar[i] = 0;
    }
    int d = (int)(idx & 255);
    int t = (int)((idx >> 8) & 511);
    int b = (int)(idx >> 17);
    xT[((size_t)(t * 32 + b) << 8) | d] = (bf16)inp[idx];
}

__global__ void k_movmean(const bf16* __restrict__ xT, bf16* __restrict__ out,
                          int s) {
    size_t idx = (size_t)blockIdx.x * 256 + threadIdx.x;
    int d = (int)(idx & 255);
    int m = (int)(idx >> 8);
    int t = m >> 5, b = m & 31;
    float acc = 0.f;
    for (int i = 0; i < s; ++i)
        acc += (float)xT[(((size_t)(t + i) * 32 + b) << 8) | d];
    out[idx] = (bf16)(acc * (1.f / (float)s));
}

// ---------------------------------------------------------------------------
// Tiled MFMA GEMM, 128x128 tile, BK=64, global_load_lds(16B) staging with
// XOR chunk swizzle (chunk q of row m at q^(m&7)). C = A1·W1^T (+ A2·W2^T)
// + biases (fp32). Cf!=null: fp32 out; else bf16 Cb. Stores guarded (Mstore).
// ---------------------------------------------------------------------------
__global__ __launch_bounds__(256, 2) void k_gemm(
    const bf16* __restrict__ A1, int lda1, const bf16* __restrict__ W1, int nk1,
    const bf16* __restrict__ A2, int lda2, const bf16* __restrict__ W2, int nk2,
    const float* __restrict__ bias1, const float* __restrict__ bias2,
    float* __restrict__ Cf, bf16* __restrict__ Cb, int ldc, int Mstore) {
    __shared__ bf16 lsA[128 * 64];
    __shared__ bf16 lsW[128 * 64];
    const int tid = threadIdx.x;
    const int lane = tid & 63, w = tid >> 6;
    const int quad = lane >> 4, lr = lane & 15;
    const int wm = w >> 1, wn = w & 1;
    const int m0 = blockIdx.y * 128, n0 = blockIdx.x * 128;

    floatx4 acc[4][4] = {};

    const bf16* As[2] = {A1, A2};
    const bf16* Ws[2] = {W1, W2};
    const int ldas[2] = {lda1, lda2};
    const int nks[2] = {nk1, nk2};

    for (int ph = 0; ph < 2; ++ph) {
        const int nk = nks[ph];
        if (nk == 0) continue;
        const bf16* A = As[ph];
        const bf16* Wp = Ws[ph];
        const int lda = ldas[ph];
        const int ldw = nk * 64;
        for (int kb = 0; kb < nk; ++kb) {
            const bf16* Ab = A + (size_t)m0 * lda + (size_t)kb * 64;
            const bf16* Wb = Wp + (size_t)n0 * ldw + (size_t)kb * 64;
#pragma unroll
            for (int i = 0; i < 4; ++i) {
                int c = (i * 4 + w) * 64 + lane;
                int m = c >> 3, q = c & 7;
                const bf16* g1 = Ab + (size_t)m * lda + ((q ^ (m & 7)) << 3);
                __builtin_amdgcn_global_load_lds((const gvoid*)g1,
                                                 (lvoid*)(lsA + (i * 4 + w) * 512), 16, 0, 0);
                const bf16* g2 = Wb + (size_t)m * ldw + ((q ^ (m & 7)) << 3);
                __builtin_amdgcn_global_load_lds((const gvoid*)g2,
                                                 (lvoid*)(lsW + (i * 4 + w) * 512), 16, 0, 0);
            }
            __syncthreads();
#pragma unroll
            for (int s = 0; s < 2; ++s) {
                bf16x8 af[4], bfr[4];
#pragma unroll
                for (int i = 0; i < 4; ++i) {
                    int kc = s * 4 + quad;
                    int m = wm * 64 + i * 16 + lr;
                    af[i] = *(const bf16x8*)(lsA + m * 64 + ((kc ^ (m & 7)) << 3));
                    int n = wn * 64 + i * 16 + lr;
                    bfr[i] = *(const bf16x8*)(lsW + n * 64 + ((kc ^ (n & 7)) << 3));
                }
#pragma unroll
                for (int i = 0; i < 4; ++i)
#pragma unroll
                    for (int j = 0; j < 4; ++j)
                        acc[i][j] = MFMA16(af[i], bfr[j], acc[i][j]);
            }
            __syncthreads();
        }
    }

    // Epilogue (C/D layout: col = lane&15, row = quad*4 + reg).
#pragma unroll
    for (int j = 0; j < 4; ++j) {
        int col = n0 + wn * 64 + j * 16 + lr;
        float bs = 0.f;
        if (bias1) bs += bias1[col];
        if (bias2) bs += bias2[col];
#pragma unroll
        for (int i = 0; i < 4; ++i) {
            int rowb = m0 + wm * 64 + i * 16 + quad * 4;
#pragma unroll
            for (int r = 0; r < 4; ++r) {
                int row = rowb + r;
                if (row < Mstore) {
                    float v = acc[i][j][r] + bs;
                    if (Cf) Cf[(size_t)row * ldc + col] = v;
                    else    Cb[(size_t)row * ldc + col] = (bf16)v;
                }
            }
        }
    }
}

// ---------------------------------------------------------------------------
// Persistent GRU recurrence over a chunk of T steps. 64 blocks x 384 threads
// (6 waves = 2 Mtiles x 3 gates). Block blk owns hidden cols [blk*16,+16).
//
// Round-6 protocol; round-7 data-path changes:
//   * Whh B-fragments live in 128 VGPRs per thread (loaded ONCE from global)
//     -> no lw in LDS, halves per-step LDS read traffic (384KB -> 192KB).
//   * hT uses padded row stride 1040 bf16 (2080B: 16B-aligned, bank-group
//     balanced) instead of XOR swizzle -> conflict-free reads & writes.
//   * gh has its own LDS buffer (no alias) -> one barrier fewer per step.
// Per step: stage h (sc1 loads, issue-all/write-all) | S1 | MFMA (A from LDS,
// B from regs) + gh write | S2 | gates + h publish | S3 (drain 1KB publish) |
// flag | deferred G-prefetch + outs | poll | S4.
// LDS: hT 32x1040 bf16 (66,560B) + gh 96x17 fp32 (6,528B) = 73,088B.
// ---------------------------------------------------------------------------
__global__ __launch_bounds__(384, 1) void k_rec(
    const float* __restrict__ G, const bf16* __restrict__ Whh,
    const float* __restrict__ bhh, bf16* __restrict__ outs,
    bf16* __restrict__ h01, float* __restrict__ hf,
    float* __restrict__ hid_out, uint* __restrict__ bar,
    int T, int init, int final_, uint tgt0) {
    const int tid = threadIdx.x, blk = blockIdx.x;
    const int lane = tid & 63, w = tid >> 6;
    const int quad = lane >> 4, lr = lane & 15;
    const int mi = (w >= 3) ? 1 : 0, ni = w - mi * 3;

    __shared__ __attribute__((aligned(16))) char smem[73088];
    bf16* hT = (bf16*)smem;              // 32 rows x HSTR bf16, 66,560B
    float* gh = (float*)(smem + 66560);  // 96 x 17 fp32, 6,528B

    // Whh B-fragments -> registers, one-time load. breg[kt] holds
    // Whh[ni*1024 + blk*16 + lr][ (quad + kt*4)*8 .. +8 ).
    const bf16* wrow = Whh + ((size_t)ni * 1024 + blk * 16 + lr) * 1024 + quad * 8;
    bf16x8 breg[32];
#pragma unroll
    for (int kt = 0; kt < 32; ++kt)
        breg[kt] = *(const bf16x8*)(wrow + kt * 32);

    // Elementwise mapping: thread (tid<256) owns batch row eb, col pair ec.
    const int eb = tid >> 3;
    const int ec = (tid & 7) * 2;
    const int ecg = blk * 16 + ec;

    float bhr0 = 0.f, bhr1 = 0.f, bhi0 = 0.f, bhi1 = 0.f, bhn0 = 0.f, bhn1 = 0.f;
    float hreg0 = 0.f, hreg1 = 0.f;
    if (tid < 256) {
        bhr0 = bhh[ecg];        bhr1 = bhh[ecg + 1];
        bhi0 = bhh[1024 + ecg]; bhi1 = bhh[1024 + ecg + 1];
        bhn0 = bhh[2048 + ecg]; bhn1 = bhh[2048 + ecg + 1];
        if (!init) {
            floatx2 h = *(const floatx2*)(hf + (size_t)eb * 1024 + ecg);
            hreg0 = h.x;
            hreg1 = h.y;
        }
        union { bf16 h[2]; uint u; } pk;
        pk.h[0] = (bf16)hreg0;
        pk.h[1] = (bf16)hreg1;
        __hip_atomic_store((uint*)(h01 + (size_t)eb * 1024 + ecg), pk.u,
                           __ATOMIC_RELAXED, __HIP_MEMORY_SCOPE_AGENT);
    }

    // G prefetch registers: pA = current step, pB = next step.
    floatx2 pAr, pAi, pAn, pBr, pBi, pBn;
    if (tid < 256) {
        const float* Grow = G + (size_t)eb * 3072 + ecg;
        pAr = *(const floatx2*)(Grow);
        pAi = *(const floatx2*)(Grow + 1024);
        pAn = *(const floatx2*)(Grow + 2048);
    }

    uint* myflag = bar + (uint)blk * FLAG_STRIDE;

    __syncthreads();  // drains h01 sc1 stores (vmcnt(0) before s_barrier)
    if (tid == 0)
        __hip_atomic_store(myflag, tgt0, __ATOMIC_RELAXED, __HIP_MEMORY_SCOPE_AGENT);
    if (tid < NB_REC) {
        const uint* fp = bar + (uint)tid * FLAG_STRIDE;
        while (__hip_atomic_load(fp, __ATOMIC_RELAXED, __HIP_MEMORY_SCOPE_AGENT) < tgt0)
            __builtin_amdgcn_s_sleep(1);
    }
    __syncthreads();

    for (int t = 0; t < T; ++t) {
        const bf16* hb = h01 + (size_t)(t & 1) * (32 * 1024);
        bf16* hn = h01 + (size_t)((t + 1) & 1) * (32 * 1024);

        // --- Stage h tile -> LDS (sc1 loads, issue-all then write-all).
        //     Padded layout: chunk q of row m at hT[m*HSTR + q*8].
        u64 s0[11], s1[11];
#pragma unroll
        for (int r = 0; r < 11; ++r) {
            int ci = tid + r * 384;
            if (r < 10 || ci < 4096) {
                const u64* src = (const u64*)(hb + (size_t)ci * 8);
                s0[r] = __hip_atomic_load(src, __ATOMIC_RELAXED, __HIP_MEMORY_SCOPE_AGENT);
                s1[r] = __hip_atomic_load(src + 1, __ATOMIC_RELAXED, __HIP_MEMORY_SCOPE_AGENT);
            }
        }
#pragma unroll
        for (int r = 0; r < 11; ++r) {
            int ci = tid + r * 384;
            if (r < 10 || ci < 4096) {
                int row = ci >> 7, q = ci & 127;
                u64x2 v;
                v.x = s0[r];
                v.y = s1[r];
                *(u64x2*)(hT + row * HSTR + q * 8) = v;
            }
        }
        __syncthreads();  // S1: hT staged

        // --- MFMA: gh(partial) = h @ Whh_slice^T; A from LDS, B from regs --
        floatx4 acc0 = {0.f, 0.f, 0.f, 0.f}, acc1 = {0.f, 0.f, 0.f, 0.f};
        const bf16* aB = hT + (mi * 16 + lr) * HSTR + quad * 8;
#pragma unroll
        for (int kt = 0; kt < 32; kt += 2) {
            bf16x8 a0 = *(const bf16x8*)(aB + kt * 32);
            acc0 = MFMA16(a0, breg[kt], acc0);
            bf16x8 a1 = *(const bf16x8*)(aB + kt * 32 + 32);
            acc1 = MFMA16(a1, breg[kt + 1], acc1);
        }
        floatx4 acc = acc0 + acc1;
#pragma unroll
        for (int r = 0; r < 4; ++r)
            gh[(ni * 32 + mi * 16 + quad * 4 + r) * 17 + lr] = acc[r];
        __syncthreads();  // S2: gh ready

        uint pku = 0u;
        if (tid < 256) {
            float ghr0 = gh[eb * 17 + ec]            + bhr0;
            float ghr1 = gh[eb * 17 + ec + 1]        + bhr1;
            float ghi0 = gh[(32 + eb) * 17 + ec]     + bhi0;
            float ghi1 = gh[(32 + eb) * 17 + ec + 1] + bhi1;
            float ghn0 = gh[(64 + eb) * 17 + ec]     + bhn0;
            float ghn1 = gh[(64 + eb) * 17 + ec + 1] + bhn1;
            float rg0 = 1.f / (1.f + __expf(-(pAr.x + ghr0)));
            float rg1 = 1.f / (1.f + __expf(-(pAr.y + ghr1)));
            float ig0 = 1.f / (1.f + __expf(-(pAi.x + ghi0)));
            float ig1 = 1.f / (1.f + __expf(-(pAi.y + ghi1)));
            float pre0 = pAn.x + rg0 * ghn0;
            float pre1 = pAn.y + rg1 * ghn1;
            float e20 = __expf(2.f * pre0);
            float e21 = __expf(2.f * pre1);
            float ng0 = 1.f - 2.f / (e20 + 1.f);  // tanh(pre)
            float ng1 = 1.f - 2.f / (e21 + 1.f);
            hreg0 = ng0 + ig0 * (hreg0 - ng0);
            hreg1 = ng1 + ig1 * (hreg1 - ng1);
            union { bf16 h[2]; uint u; } pk;
            pk.h[0] = (bf16)hreg0;
            pk.h[1] = (bf16)hreg1;
            pku = pk.u;
            // Publish h_{t+1} (sc1): the ONLY memory op the next sync drains.
            __hip_atomic_store((uint*)(hn + (size_t)eb * 1024 + ecg), pku,
                               __ATOMIC_RELAXED, __HIP_MEMORY_SCOPE_AGENT);
        }
        __syncthreads();  // S3: drains just the 1KB h publish

        uint tgt = tgt0 + 1 + (uint)t;
        if (tid == 0)
            __hip_atomic_store(myflag, tgt, __ATOMIC_RELAXED, __HIP_MEMORY_SCOPE_AGENT);

        // Deferred traffic: next-step G prefetch + outs store drain under the
        // poll window, not on the flag-release path.
        if (tid < 256) {
            if (t + 1 < T) {
                const float* Grow = G + ((size_t)(t + 1) * 32 + eb) * 3072 + ecg;
                pBr = *(const floatx2*)(Grow);
                pBi = *(const floatx2*)(Grow + 1024);
                pBn = *(const floatx2*)(Grow + 2048);
            }
            *(uint*)(outs + ((size_t)t * 32 + eb) * 1024 + ecg) = pku;
        }
        if (t + 1 < T && tid < NB_REC) {
            const uint* fp = bar + (uint)tid * FLAG_STRIDE;
            while (__hip_atomic_load(fp, __ATOMIC_RELAXED, __HIP_MEMORY_SCOPE_AGENT) < tgt)
                __builtin_amdgcn_s_sleep(1);
        }
        __syncthreads();  // S4

        pAr = pBr; pAi = pBi; pAn = pBn;
    }

    if (tid < 256) {
        floatx2 h;
        h.x = hreg0;
        h.y = hreg1;
        *(floatx2*)(hf + (size_t)eb * 1024 + ecg) = h;
        if (final_)
            *(floatx2*)(hid_out + (size_t)eb * 1024 + ecg) = h;
    }
}

// ---------------------------------------------------------------------------
extern "C" void kernel_launch(void* const* d_in, const int* in_sizes, int n_in,
                              void* d_out, int out_size, void* d_ws, size_t ws_size,
                              hipStream_t stream) {
    const float* inp  = (const float*)d_in[0];
    const float* Wxh0 = (const float*)d_in[1];
    const float* bxh0 = (const float*)d_in[2];
    const float* Whh0 = (const float*)d_in[3];
    const float* bhh0 = (const float*)d_in[4];
    const float* Wnh0 = (const float*)d_in[5];
    const float* bnh0 = (const float*)d_in[6];
    const float* Wxh1 = (const float*)d_in[7];
    const float* bxh1 = (const float*)d_in[8];
    const float* Whh1 = (const float*)d_in[9];
    const float* bhh1 = (const float*)d_in[10];
    const float* Wnh1 = (const float*)d_in[11];
    const float* bnh1 = (const float*)d_in[12];
    const float* Wxh2 = (const float*)d_in[13];
    const float* bxh2 = (const float*)d_in[14];
    const float* Whh2 = (const float*)d_in[15];
    const float* bhh2 = (const float*)d_in[16];
    const float* Wnh2 = (const float*)d_in[17];
    const float* bnh2 = (const float*)d_in[18];
    const float* Wout = (const float*)d_in[19];
    const float* bout = (const float*)d_in[20];
    float* out = (float*)d_out;  // reference output dtype is float32

    char* ws = (char*)d_ws;
    size_t o = 0;
    auto take = [&](size_t bytes) {
        o = (o + 255) & ~(size_t)255;
        char* p = ws + o;
        o += bytes;
        return p;
    };
    const size_t RP = 16512;  // row padding: covers GEMM A-tile overread
    bf16* xT    = (bf16*)take(RP * 256 * 2);
    bf16* ms1   = (bf16*)take(RP * 256 * 2);
    bf16* ms2   = (bf16*)take(RP * 256 * 2);
    bf16* outs0 = (bf16*)take(RP * 1024 * 2);
    bf16* outs1 = (bf16*)take(RP * 1024 * 2);
    bf16* outs2 = outs0;  // alias: outs0 dead after proj0 (launched first)
    bf16* h01   = (bf16*)take((size_t)2 * 32 * 1024 * 2);
    float* hf   = (float*)take((size_t)32 * 1024 * 4);
    uint* bar   = (uint*)take((size_t)3 * NB_REC * FLAG_STRIDE * 4);
    bf16* wXh = (bf16*)take((size_t)3072 * 1024 * 2);
    bf16* wNh = (bf16*)take((size_t)3072 * 256 * 2);
    bf16* wHh = (bf16*)take((size_t)3072 * 1024 * 2);
    bf16* wOut = (bf16*)take((size_t)256 * 1024 * 2);
    o = (o + 255) & ~(size_t)255;

    size_t avail = (ws_size > o) ? (ws_size - o) : 0;
    int CT = (int)(avail / ((size_t)32 * 3072 * 4));
    if (CT > 512) CT = 512;
    if (CT < 4) CT = 4;
    float* G = (float*)(ws + o);
    (void)in_sizes; (void)n_in; (void)out_size;

    const size_t o0 = 0, o1 = (size_t)512 * 32 * 256, o2 = o1 + (size_t)511 * 32 * 256;
    const size_t ohid = o2 + (size_t)509 * 32 * 256;

    auto cvt = [&](const float* s, bf16* d, int n) {
        k_cvt<<<(n + 255) / 256, 256, 0, stream>>>(s, d, n);
    };
    cvt(Wout, wOut, 256 * 1024);
    k_prep<<<16384, 256, 0, stream>>>(inp, xT, bar);
    k_movmean<<<511 * 32, 256, 0, stream>>>(xT, ms1, 2);
    k_movmean<<<509 * 32, 256, 0, stream>>>(xT, ms2, 4);

    auto run_layer = [&](const bf16* xs, int ldx, const float* Wxh, int nkx,
                         const bf16* ms, const float* Wnh,
                         const float* bxh, const float* bnh,
                         const float* Whh, const float* bhh,
                         bf16* outs, float* hid, int T, int layer) {
        cvt(Wxh, wXh, 3072 * nkx * 64);
        cvt(Wnh, wNh, 3072 * 256);
        cvt(Whh, wHh, 3072 * 1024);
        uint base = 0;
        for (int t0 = 0; t0 < T; t0 += CT) {
            int ct = (T - t0 < CT) ? (T - t0) : CT;
            int gy = (ct * 32 + 127) / 128;
            k_gemm<<<dim3(24, gy), 256, 0, stream>>>(
                xs + (size_t)t0 * 32 * ldx, ldx, wXh, nkx,
                ms + (size_t)t0 * 32 * 256, 256, wNh, 4,
                bxh, bnh, G, (bf16*)nullptr, 3072, ct * 32);
            k_rec<<<NB_REC, 384, 0, stream>>>(
                G, wHh, bhh, outs + (size_t)t0 * 32 * 1024, h01, hf, hid,
                bar + (size_t)NB_REC * FLAG_STRIDE * layer, ct,
                (t0 == 0) ? 1 : 0, (t0 + ct >= T) ? 1 : 0, base + 1);
            base += (uint)ct + 1;
        }
    };

    // Layer 0 (ms0 == x): G = x@Wxh0^T + x@Wnh0^T + bxh0 + bnh0
    run_layer(xT, 256, Wxh0, 4, xT, Wnh0, bxh0, bnh0, Whh0, bhh0,
              outs0, out + ohid, 512, 0);
    // Layer 1: xs = outs0[1:], ms = ms1
    run_layer(outs0 + (size_t)32 * 1024, 1024, Wxh1, 16, ms1, Wnh1,
              bxh1, bnh1, Whh1, bhh1, outs1, out + ohid + 32768, 511, 1);
    // Projection of layer-0 outs BEFORE layer 2 overwrites the aliased buffer.
    k_gemm<<<dim3(2, 128), 256, 0, stream>>>(outs0, 1024, wOut, 16,
                                             nullptr, 0, nullptr, 0, bout, nullptr,
                                             out + o0, nullptr, 256, 16384);
    // Layer 2: xs = outs1[2:], ms = ms2; outs2 aliases outs0.
    run_layer(outs1 + (size_t)64 * 1024, 1024, Wxh2, 16, ms2, Wnh2,
              bxh2, bnh2, Whh2, bhh2, outs2, out + ohid + 65536, 509, 2);

    k_gemm<<<dim3(2, 128), 256, 0, stream>>>(outs1, 1024, wOut, 16,
                                             nullptr, 0, nullptr, 0, bout, nullptr,
                                             out + o1, nullptr, 256, 16352);
    k_gemm<<<dim3(2, 128), 256, 0, stream>>>(outs2, 1024, wOut, 16,
                                             nullptr, 0, nullptr, 0, bout, nullptr,
                                             out + o2, nullptr, 256, 16288);
}